// Round 2
// baseline (1264.658 us; speedup 1.0000x reference)
//
#include <hip/hip_runtime.h>
#include <hip/hip_bf16.h>
#include <stdint.h>

// ---------- types ----------
typedef __bf16  bf16x8  __attribute__((ext_vector_type(8)));
typedef float   f32x4   __attribute__((ext_vector_type(4)));
typedef unsigned short ushort_t;

__device__ __forceinline__ unsigned short f2b(float f) {
    __hip_bfloat16 h = __float2bfloat16(f);   // RNE
    return *reinterpret_cast<unsigned short*>(&h);
}

// dims
#define BB 8
#define LL 2048
#define DM 64
#define NH 4
#define DK 64

// ---------- K0: pack mask int32 -> bits (k-major, 32 keys/word) ----------
__global__ __launch_bounds__(256) void k_maskpack(const int* __restrict__ mask,
                                                  unsigned int* __restrict__ words) {
    int tid = blockIdx.x * 256 + threadIdx.x;        // over 8*2048*2048
    int m = mask[tid];
    unsigned long long bal = __ballot(m != 0);
    if ((threadIdx.x & 63) == 0) {
        int w0 = tid >> 5;                            // tid is 64-aligned here
        words[w0]     = (unsigned int)(bal & 0xffffffffull);
        words[w0 + 1] = (unsigned int)(bal >> 32);
    }
}

// ---------- K1: gates S_q,S_k,S_v per batch ----------
__global__ __launch_bounds__(64) void k_gates(const float* __restrict__ u,
                                              const float* s1q, const float* s2q,
                                              const float* s1k, const float* s2k,
                                              const float* s1v, const float* s2v,
                                              float* __restrict__ gates) {
    int b = blockIdx.x, g = blockIdx.y, lane = threadIdx.x;
    const float* s1 = (g == 0) ? s1q : (g == 1) ? s1k : s1v;
    const float* s2 = (g == 0) ? s2q : (g == 1) ? s2k : s2v;
    float ur = u[b * 64 + lane];
    float acc = 0.f;
    for (int j = 0; j < 64; j++) {
        float uj = __shfl(ur, j, 64);
        if (lane < 32) acc += uj * s1[j * 32 + lane];
    }
    float r = (lane < 32) ? fmaxf(acc, 0.f) * s2[lane] : 0.f;
    for (int m = 32; m >= 1; m >>= 1) r += __shfl_xor(r, m, 64);
    if (lane == 0) gates[b * 3 + g] = r;
}

// ---------- K2: projections -> Qe [b,h,L,128] (scaled 1/8), Ke [b,h,L,128], Ve=V+uV [b,h,L,64] (bf16) ----------
__global__ __launch_bounds__(256) void k_proj(const float* __restrict__ x,
                                              const float* __restrict__ wq,
                                              const float* __restrict__ wk,
                                              const float* __restrict__ wv,
                                              const float* __restrict__ uqw,
                                              const float* __restrict__ ukw,
                                              const float* __restrict__ uvw,
                                              const float* __restrict__ gates,
                                              ushort_t* __restrict__ Qe,
                                              ushort_t* __restrict__ Ke,
                                              ushort_t* __restrict__ Ve) {
    int lt = blockIdx.x, b = blockIdx.y, t = threadIdx.x;
    int l0 = lt * 32;
    __shared__ float lx[32][64];
    __shared__ float luv[32][64];
    #pragma unroll
    for (int i = 0; i < 2; i++) {      // stage x tile: 32x64 floats
        int id = t + i * 256;          // 0..511
        int r = id >> 4, c4 = id & 15;
        float4 v = *(const float4*)&x[((b * LL) + l0 + r) * 64 + c4 * 4];
        lx[r][c4 * 4 + 0] = v.x; lx[r][c4 * 4 + 1] = v.y;
        lx[r][c4 * 4 + 2] = v.z; lx[r][c4 * 4 + 3] = v.w;
    }
    __syncthreads();
    float Sq = gates[b * 3 + 0], Sk = gates[b * 3 + 1], Sv = gates[b * 3 + 2];
    // u-projections (waves 0..2)
    if (t < 192) {
        int m = t >> 6, d = t & 63;
        const float* uw = (m == 0) ? uqw : (m == 1) ? ukw : uvw;
        float acc[32];
        #pragma unroll
        for (int r = 0; r < 32; r++) acc[r] = 0.f;
        for (int j = 0; j < 64; j++) {
            float w = uw[j * 64 + d];
            #pragma unroll
            for (int r = 0; r < 32; r++) acc[r] += lx[r][j] * w;
        }
        if (m == 2) {
            for (int r = 0; r < 32; r++) luv[r][d] = acc[r] * Sv;
        } else {
            ushort_t* dst = (m == 0) ? Qe : Ke;
            float sc = (m == 0) ? Sq * 0.125f : Sk;
            for (int r = 0; r < 32; r++) {
                unsigned short v = f2b(acc[r] * sc);
                int base = ((b * NH) * LL + l0 + r) * 128 + 64 + d;
                #pragma unroll
                for (int h = 0; h < 4; h++) dst[base + h * (LL * 128)] = v;
            }
        }
    }
    __syncthreads();
    // head projections: thread = output column c of [Q|K|V] (256 cols)
    int c = t, hh = c >> 6, d = c & 63;
    {
        float acc[32];
        #pragma unroll
        for (int r = 0; r < 32; r++) acc[r] = 0.f;
        for (int j = 0; j < 64; j++) {
            float w = wq[j * 256 + c];
            #pragma unroll
            for (int r = 0; r < 32; r++) acc[r] += lx[r][j] * w;
        }
        for (int r = 0; r < 32; r++)
            Qe[((b * NH + hh) * LL + l0 + r) * 128 + d] = f2b(acc[r] * 0.125f);
    }
    {
        float acc[32];
        #pragma unroll
        for (int r = 0; r < 32; r++) acc[r] = 0.f;
        for (int j = 0; j < 64; j++) {
            float w = wk[j * 256 + c];
            #pragma unroll
            for (int r = 0; r < 32; r++) acc[r] += lx[r][j] * w;
        }
        for (int r = 0; r < 32; r++)
            Ke[((b * NH + hh) * LL + l0 + r) * 128 + d] = f2b(acc[r]);
    }
    {
        float acc[32];
        #pragma unroll
        for (int r = 0; r < 32; r++) acc[r] = 0.f;
        for (int j = 0; j < 64; j++) {
            float w = wv[j * 256 + c];
            #pragma unroll
            for (int r = 0; r < 32; r++) acc[r] += lx[r][j] * w;
        }
        for (int r = 0; r < 32; r++)
            Ve[((b * NH + hh) * LL + l0 + r) * 64 + d] = f2b(acc[r] + luv[r][d]);
    }
}

// ---------- K3: attention core (two-pass over K) ----------
// grid (32 qtiles, 4 heads, 8 batches), 256 threads (4 waves x 16 q-rows)
__global__ __launch_bounds__(256) void k_attn(const ushort_t* __restrict__ Qe,
                                              const ushort_t* __restrict__ Ke,
                                              const ushort_t* __restrict__ Ve,
                                              const unsigned int* __restrict__ mwords,
                                              float* __restrict__ ctx,
                                              float* __restrict__ attn) {
    int qt = blockIdx.x, h = blockIdx.y, b = blockIdx.z;
    int t = threadIdx.x, w = t >> 6, lane = t & 63, quad = lane >> 4, l15 = lane & 15;
    int q0 = qt * 64;
    int bh = b * NH + h;
    const ushort_t* QeB = Qe + (long)bh * LL * 128;
    const ushort_t* KeB = Ke + (long)bh * LL * 128;
    const ushort_t* VeB = Ve + (long)bh * LL * 64;
    float* attnB = attn + (long)bh * LL * LL;
    const unsigned int* mB = mwords + (long)(b * LL) * 64;

    __shared__ unsigned int  smask[64][66];   // q-tile mask words, +2 pad
    __shared__ unsigned short sKe[64][136];   // Ke tile 64x128 (+8 pad)
    __shared__ unsigned short sVT[64][72];    // Ve transposed: [d][key]
    __shared__ unsigned short sPb[4][16][72]; // per-wave P tile [q][key] bf16

    // stage this q-tile's mask bits (64 rows x 64 words)
    #pragma unroll
    for (int i = 0; i < 16; i++) {
        int id = t + i * 256;
        smask[id >> 6][id & 63] = mB[(q0 + (id >> 6)) * 64 + (id & 63)];
    }

    // Q fragments for this wave's 16 rows (resident whole kernel)
    bf16x8 aq[4];
    int qrow = q0 + w * 16 + l15;
    #pragma unroll
    for (int c = 0; c < 4; c++)
        aq[c] = *(const bf16x8*)&QeB[qrow * 128 + c * 32 + quad * 8];

    float lsum[4] = {0.f, 0.f, 0.f, 0.f};
    int mrow = w * 16 + quad * 4;              // this lane's first mask row

    // ---- pass A: row sums ----
    for (int kt = 0; kt < 32; kt++) {
        int k0 = kt * 64;
        __syncthreads();
        #pragma unroll
        for (int i = 0; i < 4; i++) {
            int cch = t + i * 256, key = cch >> 4, f8 = cch & 15;
            *(bf16x8*)&sKe[key][f8 * 8] = *(const bf16x8*)&KeB[(k0 + key) * 128 + f8 * 8];
        }
        __syncthreads();
        #pragma unroll
        for (int nb = 0; nb < 4; nb++) {
            f32x4 s = (f32x4){0.f, 0.f, 0.f, 0.f};
            #pragma unroll
            for (int c = 0; c < 4; c++) {
                bf16x8 kb = *(const bf16x8*)&sKe[nb * 16 + l15][c * 32 + quad * 8];
                s = __builtin_amdgcn_mfma_f32_16x16x32_bf16(aq[c], kb, s, 0, 0, 0);
            }
            #pragma unroll
            for (int reg = 0; reg < 4; reg++) {
                unsigned int word = smask[mrow + reg][kt * 2 + (nb >> 1)];
                unsigned int bit = (word >> ((nb & 1) * 16 + l15)) & 1u;
                lsum[reg] += bit ? 0.f : __expf(fminf(s[reg], 60.f));
            }
        }
    }
    // row sums: reduce across the 16 lanes holding a row's columns
    float inv[4];
    #pragma unroll
    for (int reg = 0; reg < 4; reg++) {
        float v = lsum[reg];
        #pragma unroll
        for (int m = 1; m < 16; m <<= 1) v += __shfl_xor(v, m, 16);
        inv[reg] = (v > 0.f) ? 1.f / v : 0.f;
    }

    // ---- pass B: normalized attn store + PV ----
    f32x4 cacc[4];
    #pragma unroll
    for (int db = 0; db < 4; db++) cacc[db] = (f32x4){0.f, 0.f, 0.f, 0.f};

    for (int kt = 0; kt < 32; kt++) {
        int k0 = kt * 64;
        __syncthreads();
        #pragma unroll
        for (int i = 0; i < 4; i++) {
            int cch = t + i * 256, key = cch >> 4, f8 = cch & 15;
            *(bf16x8*)&sKe[key][f8 * 8] = *(const bf16x8*)&KeB[(k0 + key) * 128 + f8 * 8];
        }
        #pragma unroll
        for (int i = 0; i < 2; i++) {   // Ve tile transposed -> sVT[d][key]
            int cch = t + i * 256, key = cch >> 3, d8 = cch & 7;
            float4 dummy;  // (unused) keep loads vectorized below
            const ushort_t* src = &VeB[(k0 + key) * 64 + d8 * 8];
            ushort_t v0 = src[0], v1 = src[1], v2 = src[2], v3 = src[3];
            ushort_t v4 = src[4], v5 = src[5], v6 = src[6], v7 = src[7];
            sVT[d8 * 8 + 0][key] = v0; sVT[d8 * 8 + 1][key] = v1;
            sVT[d8 * 8 + 2][key] = v2; sVT[d8 * 8 + 3][key] = v3;
            sVT[d8 * 8 + 4][key] = v4; sVT[d8 * 8 + 5][key] = v5;
            sVT[d8 * 8 + 6][key] = v6; sVT[d8 * 8 + 7][key] = v7;
            (void)dummy;
        }
        __syncthreads();
        #pragma unroll
        for (int nb = 0; nb < 4; nb++) {
            f32x4 s = (f32x4){0.f, 0.f, 0.f, 0.f};
            #pragma unroll
            for (int c = 0; c < 4; c++) {
                bf16x8 kb = *(const bf16x8*)&sKe[nb * 16 + l15][c * 32 + quad * 8];
                s = __builtin_amdgcn_mfma_f32_16x16x32_bf16(aq[c], kb, s, 0, 0, 0);
            }
            #pragma unroll
            for (int reg = 0; reg < 4; reg++) {
                unsigned int word = smask[mrow + reg][kt * 2 + (nb >> 1)];
                unsigned int bit = (word >> ((nb & 1) * 16 + l15)) & 1u;
                float p = bit ? 0.f : __expf(fminf(s[reg], 60.f));
                sPb[w][quad * 4 + reg][nb * 16 + l15] = f2b(p);
                attnB[(long)(q0 + mrow + reg) * LL + k0 + nb * 16 + l15] = p * inv[reg];
            }
        }
        // ctx += P @ Ve   (unnormalized P; normalized at the end)
        #pragma unroll
        for (int db = 0; db < 4; db++) {
            #pragma unroll
            for (int c2 = 0; c2 < 2; c2++) {
                bf16x8 a  = *(const bf16x8*)&sPb[w][l15][c2 * 32 + quad * 8];
                bf16x8 bb = *(const bf16x8*)&sVT[db * 16 + l15][c2 * 32 + quad * 8];
                cacc[db] = __builtin_amdgcn_mfma_f32_16x16x32_bf16(a, bb, cacc[db], 0, 0, 0);
            }
        }
    }
    // normalized ctx -> ws [b,L,256] fp32
    #pragma unroll
    for (int db = 0; db < 4; db++)
        #pragma unroll
        for (int reg = 0; reg < 4; reg++) {
            int qr = q0 + mrow + reg;
            ctx[((long)(b * LL) + qr) * 256 + h * 64 + db * 16 + l15] = cacc[db][reg] * inv[reg];
        }
}

// ---------- K5: fc + residual + LN1 + FFN + LN2 ----------
__global__ __launch_bounds__(256) void k_epi(const float* __restrict__ ctx,
                                             const float* __restrict__ x,
                                             const float* __restrict__ fcw,
                                             const float* __restrict__ g1,
                                             const float* __restrict__ b1,
                                             const float* __restrict__ f1,
                                             const float* __restrict__ f2,
                                             const float* __restrict__ g2,
                                             const float* __restrict__ b2w,
                                             float* __restrict__ res) {
    int w = threadIdx.x >> 6, lane = threadIdx.x & 63;
    int row = blockIdx.x * 4 + w;
    const float* cr = ctx + (long)row * 256;
    float creg[4];
    #pragma unroll
    for (int i = 0; i < 4; i++) creg[i] = cr[i * 64 + lane];
    float acc = 0.f;
    #pragma unroll
    for (int j = 0; j < 256; j++) {
        float cj = __shfl(creg[j >> 6], j & 63, 64);
        acc += cj * fcw[j * 64 + lane];
    }
    float val = acc + x[row * 64 + lane];
    float mu = val;
    #pragma unroll
    for (int m = 1; m < 64; m <<= 1) mu += __shfl_xor(mu, m, 64);
    mu *= (1.f / 64.f);
    float d0 = val - mu;
    float var = d0 * d0;
    #pragma unroll
    for (int m = 1; m < 64; m <<= 1) var += __shfl_xor(var, m, 64);
    var *= (1.f / 64.f);
    float enc = d0 * rsqrtf(var + 1e-5f) * g1[lane] + b1[lane];
    float a1 = 0.f;
    #pragma unroll
    for (int j = 0; j < 64; j++) a1 += __shfl(enc, j, 64) * f1[j * 64 + lane];
    float hrel = fmaxf(a1, 0.f);
    float a2 = 0.f;
    #pragma unroll
    for (int j = 0; j < 64; j++) a2 += __shfl(hrel, j, 64) * f2[j * 64 + lane];
    float v2 = a2 + enc;
    float mu2 = v2;
    #pragma unroll
    for (int m = 1; m < 64; m <<= 1) mu2 += __shfl_xor(mu2, m, 64);
    mu2 *= (1.f / 64.f);
    float d2 = v2 - mu2;
    float var2 = d2 * d2;
    #pragma unroll
    for (int m = 1; m < 64; m <<= 1) var2 += __shfl_xor(var2, m, 64);
    var2 *= (1.f / 64.f);
    float outv = d2 * rsqrtf(var2 + 1e-5f) * g2[lane] + b2w[lane];
    res[row * 64 + lane] = outv;
}

// ---------- launch ----------
extern "C" void kernel_launch(void* const* d_in, const int* in_sizes, int n_in,
                              void* d_out, int out_size, void* d_ws, size_t ws_size,
                              hipStream_t stream) {
    const float* x    = (const float*)d_in[0];
    const int*   mask = (const int*)d_in[1];
    const float* u    = (const float*)d_in[2];
    const float* wq   = (const float*)d_in[3];
    const float* wk   = (const float*)d_in[4];
    const float* wv   = (const float*)d_in[5];
    const float* uqw  = (const float*)d_in[6];
    const float* ukw  = (const float*)d_in[7];
    const float* uvw  = (const float*)d_in[8];
    const float* sq1  = (const float*)d_in[9];
    const float* sq2  = (const float*)d_in[10];
    const float* sk1  = (const float*)d_in[11];
    const float* sk2  = (const float*)d_in[12];
    const float* sv1  = (const float*)d_in[13];
    const float* sv2  = (const float*)d_in[14];
    const float* fcw  = (const float*)d_in[15];
    const float* g1   = (const float*)d_in[16];
    const float* b1   = (const float*)d_in[17];
    const float* f1   = (const float*)d_in[18];
    const float* f2   = (const float*)d_in[19];
    const float* g2   = (const float*)d_in[20];
    const float* b2w  = (const float*)d_in[21];

    char* ws = (char*)d_ws;
    float*        gates  = (float*)(ws + 0);
    unsigned int* mwords = (unsigned int*)(ws + 4096);              // 4,194,304 B
    ushort_t*     Qe     = (ushort_t*)(ws + 4198400);               // 16,777,216 B
    ushort_t*     Ke     = (ushort_t*)(ws + 20975616);              // 16,777,216 B
    ushort_t*     Ve     = (ushort_t*)(ws + 37752832);              //  8,388,608 B
    float*        ctx    = (float*)(ws + 46141440);                 // 16,777,216 B (end ~63 MB)

    float* res  = (float*)d_out;
    float* attn = (float*)d_out + (size_t)BB * LL * DM;             // offset 1,048,576 elems

    k_maskpack<<<dim3(131072), dim3(256), 0, stream>>>(mask, mwords);
    k_gates<<<dim3(8, 3), dim3(64), 0, stream>>>(u, sq1, sq2, sk1, sk2, sv1, sv2, gates);
    k_proj<<<dim3(64, 8), dim3(256), 0, stream>>>(x, wq, wk, wv, uqw, ukw, uvw, gates, Qe, Ke, Ve);
    k_attn<<<dim3(32, 4, 8), dim3(256), 0, stream>>>(Qe, Ke, Ve, mwords, ctx, attn);
    k_epi<<<dim3(4096), dim3(256), 0, stream>>>(ctx, x, fcw, g1, b1, f1, f2, g2, b2w, res);
}